// Round 4
// baseline (1478.428 us; speedup 1.0000x reference)
//
#include <hip/hip_runtime.h>
#include <stdint.h>

#define N_TOKENS 16384
#define HIDDEN   1024
#define FFN      4096
#define N_EXPERTS 8
#define NBLK     (N_TOKENS / 256)    // 64 routing blocks
#define MAX_T    136                 // worst-case 256-row tiles (sum ceil(e/256) <= 136)
#define MAX_ROWS (MAX_T * 256)       // 34816
#define NB_HALF  2048                // FFN split width (H is [rows][2048])

typedef __attribute__((ext_vector_type(8))) short short8;
typedef __attribute__((ext_vector_type(4))) float f32x4;

__device__ inline unsigned short f2bf(float f) {
  union { float f; unsigned u; } c; c.f = f;
  unsigned u = c.u;
  unsigned r = (u + 0x7fffu + ((u >> 16) & 1u)) >> 16;  // RNE
  return (unsigned short)r;
}

// R3 lesson: global_load_lds forces a compiler-inserted vmcnt(0) before every
// aliasing ds_read (LDS-DMA hazard, non-disambiguable within one __shared__
// array) -> per-phase drain regardless of source-level waits (R1==R2==R3).
// R4: reg-staged staging (global->VGPR->ds_write). All waits become exact
// per-register scoreboard waits the compiler inserts itself; ONE barrier per
// K-tile. Only sched_barrier(0) fences pin region order.
#define SCHED0() __builtin_amdgcn_sched_barrier(0)
static __device__ __forceinline__ void BAR() {
  SCHED0(); __builtin_amdgcn_s_barrier(); SCHED0();
}
#define LGKM0() do { SCHED0(); asm volatile("s_waitcnt lgkmcnt(0)"); SCHED0(); } while (0)
#define PRIO1 __builtin_amdgcn_s_setprio(1)
#define PRIO0 __builtin_amdgcn_s_setprio(0)

// ---------------- gate: scores, top-2, softmax ----------------
__global__ __launch_bounds__(256) void gate_kernel(
    const float* __restrict__ x, const float* __restrict__ Wg,
    const float* __restrict__ bg, int* __restrict__ gate_idx,
    float* __restrict__ gate_w)
{
  int lane = threadIdx.x & 63;
  int wv = threadIdx.x >> 6;
  int t = blockIdx.x * 4 + wv;
  const float* xr = x + (size_t)t * HIDDEN;
  float acc[N_EXPERTS];
#pragma unroll
  for (int e = 0; e < N_EXPERTS; e++) acc[e] = 0.f;
#pragma unroll
  for (int i = 0; i < HIDDEN / 64; i++) {
    int h = i * 64 + lane;
    float xv = xr[h];
    const float4* wv4 = (const float4*)(Wg + (size_t)h * N_EXPERTS);
    float4 w01 = wv4[0], w23 = wv4[1];
    acc[0] = fmaf(xv, w01.x, acc[0]); acc[1] = fmaf(xv, w01.y, acc[1]);
    acc[2] = fmaf(xv, w01.z, acc[2]); acc[3] = fmaf(xv, w01.w, acc[3]);
    acc[4] = fmaf(xv, w23.x, acc[4]); acc[5] = fmaf(xv, w23.y, acc[5]);
    acc[6] = fmaf(xv, w23.z, acc[6]); acc[7] = fmaf(xv, w23.w, acc[7]);
  }
#pragma unroll
  for (int off = 32; off > 0; off >>= 1)
#pragma unroll
    for (int e = 0; e < N_EXPERTS; e++)
      acc[e] += __shfl_down(acc[e], off, 64);
  if (lane == 0) {
    float s[N_EXPERTS];
#pragma unroll
    for (int e = 0; e < N_EXPERTS; e++) s[e] = acc[e] + bg[e];
    int e0 = 0;
#pragma unroll
    for (int e = 1; e < N_EXPERTS; e++) if (s[e] > s[e0]) e0 = e;
    int e1 = (e0 == 0) ? 1 : 0;
#pragma unroll
    for (int e = 0; e < N_EXPERTS; e++) if (e != e0 && s[e] > s[e1]) e1 = e;
    float d = s[e1] - s[e0];
    float ex = __expf(d);
    float w0 = 1.f / (1.f + ex);
    float w1 = ex / (1.f + ex);
    gate_idx[2 * t] = e0; gate_idx[2 * t + 1] = e1;
    gate_w[2 * t] = w0;  gate_w[2 * t + 1] = w1;
  }
}

// ---------------- per-block expert histogram ----------------
__global__ __launch_bounds__(256) void count_kernel(
    const int* __restrict__ gate_idx, int* __restrict__ blockCounts)
{
  __shared__ int h[N_EXPERTS];
  if (threadIdx.x < N_EXPERTS) h[threadIdx.x] = 0;
  __syncthreads();
  int t = blockIdx.x * 256 + threadIdx.x;
  atomicAdd(&h[gate_idx[2 * t]], 1);
  atomicAdd(&h[gate_idx[2 * t + 1]], 1);
  __syncthreads();
  if (threadIdx.x < N_EXPERTS)
    blockCounts[blockIdx.x * N_EXPERTS + threadIdx.x] = h[threadIdx.x];
}

// ---------------- scan: 256-aligned expert offsets, tile->expert ----------------
__global__ void scan_kernel(const int* __restrict__ blockCounts,
                            int* __restrict__ blockBase, int* __restrict__ meta)
{
  __shared__ int totals[N_EXPERTS];
  __shared__ int offs[N_EXPERTS + 1];
  int e = threadIdx.x;
  if (e < N_EXPERTS) {
    int run = 0;
    for (int b = 0; b < NBLK; b++) {
      blockBase[b * N_EXPERTS + e] = run;
      run += blockCounts[b * N_EXPERTS + e];
    }
    totals[e] = run;
  }
  __syncthreads();
  if (threadIdx.x == 0) {
    int off = 0;
    for (int ee = 0; ee < N_EXPERTS; ee++) {
      offs[ee] = off;
      meta[16 + ee] = off;
      off += ((totals[ee] + 255) >> 8) << 8;   // 256-aligned (BM=256)
    }
    offs[N_EXPERTS] = off;
    meta[16 + N_EXPERTS] = off;
    int ntiles = off >> 8;
    meta[25] = ntiles;
    int ee = 0;
    for (int t = 0; t < ntiles; t++) {
      while (offs[ee + 1] <= (t << 8)) ee++;
      meta[32 + t] = ee;
    }
  }
  __syncthreads();
  if (e < N_EXPERTS) {
    int o = offs[e];
    for (int b = 0; b < NBLK; b++)
      blockBase[b * N_EXPERTS + e] += o;
  }
}

// ---------------- place: slot assignment via LDS cursors ----------------
__global__ __launch_bounds__(256) void place_kernel(
    const int* __restrict__ gate_idx, const float* __restrict__ gate_w,
    const int* __restrict__ blockBase, int* __restrict__ pair_token,
    float* __restrict__ pair_w)
{
  __shared__ int cur[N_EXPERTS];
  if (threadIdx.x < N_EXPERTS)
    cur[threadIdx.x] = blockBase[blockIdx.x * N_EXPERTS + threadIdx.x];
  __syncthreads();
  int t = blockIdx.x * 256 + threadIdx.x;
#pragma unroll
  for (int k = 0; k < 2; k++) {
    int e = gate_idx[2 * t + k];
    int pos = atomicAdd(&cur[e], 1);
    pair_token[pos] = t;
    pair_w[pos] = gate_w[2 * t + k];
  }
}

// ---------------- gather x rows -> bf16 Xg ----------------
__global__ __launch_bounds__(256) void gather_kernel(
    const float* __restrict__ x, const int* __restrict__ pair_token,
    unsigned short* __restrict__ Xg)
{
  int r = blockIdx.x;
  int t = pair_token[r];
  if (t < 0) return;  // pad row: poison; dropped at GEMM2 epilogue
  const float4* src = (const float4*)(x + (size_t)t * HIDDEN);
  float4 v = src[threadIdx.x];
  ushort4 o;
  o.x = f2bf(v.x); o.y = f2bf(v.y); o.z = f2bf(v.z); o.w = f2bf(v.w);
  ((ushort4*)(Xg + (size_t)r * HIDDEN))[threadIdx.x] = o;
}

// ---------------- transpose + fp32->bf16: in[E][R][C] -> out[E][C][R] ----------------
__global__ __launch_bounds__(256) void transpose_bf16_kernel(
    const float* __restrict__ in, unsigned short* __restrict__ out, int R, int C)
{
  __shared__ float tile[64][65];
  int e = blockIdx.z;
  int r0 = blockIdx.y * 64, c0 = blockIdx.x * 64;
  int tr = threadIdx.x >> 4, tc = threadIdx.x & 15;
  const float* src = in + ((size_t)e * R + r0) * C + c0;
#pragma unroll
  for (int rr = 0; rr < 4; rr++) {
    int row = rr * 16 + tr;
    float4 v = *(const float4*)(src + (size_t)row * C + tc * 4);
    tile[row][tc * 4 + 0] = v.x; tile[row][tc * 4 + 1] = v.y;
    tile[row][tc * 4 + 2] = v.z; tile[row][tc * 4 + 3] = v.w;
  }
  __syncthreads();
  unsigned short* dst = out + ((size_t)e * C + c0) * R + r0;
#pragma unroll
  for (int rr = 0; rr < 4; rr++) {
    int crow = rr * 16 + tr;
    ushort4 o;
    o.x = f2bf(tile[tc * 4 + 0][crow]);
    o.y = f2bf(tile[tc * 4 + 1][crow]);
    o.z = f2bf(tile[tc * 4 + 2][crow]);
    o.w = f2bf(tile[tc * 4 + 3][crow]);
    *(ushort4*)(dst + (size_t)crow * R + tc * 4) = o;
  }
}

// ---------------- 256x256 bf16 GEMM, reg-staged dbuf, 1 barrier/K-tile ----------------
// BM=BN=256, BK=64, 512 threads = 8 waves (2M x 4N), per-wave 128x64 output.
// LDS: lds[buf][slot][128*64], slots 0=A-lo,1=A-hi,2=B-lo,3=B-hi. 128 KiB.
// LDS content (both bufs): LDS[r][lc] = G[r][lc ^ (r&7)] in 16B chunks (T2).
// Staging: per K-tile each thread global_loads 8x16B LINEAR into VGPRs
// (coalesced), then ds_write_b128 to the swizzled chunk (r0c*8 + c0c).
// Per tile t: [issue loads(t+1)] | SCHED0 | [ds_read frags(bi) + 64 MFMA
// (compiler-counted lgkmcnt)] | SCHED0 | [vmcnt(auto) + ds_writes -> nb] |
// lgkmcnt(0) | s_barrier.  WAR-safe: writes hit buffer nb which no wave
// touches this tile; reads of bi finished before this tile's end barrier and
// bi is rewritten only in tile t+1.
// EPI=0: H[row][hcol] = bf16(relu(acc+b1))   (A=Xg, N-window of FFN)
// EPI=1: atomicAdd(out[token][col], w*(acc+b2?))  (A=H, K-partial; bias once)
template<int EPI>
__global__ __launch_bounds__(512, 2) void moe_gemm_kernel(
    const unsigned short* __restrict__ A,    // [rows][lda] bf16
    const unsigned short* __restrict__ Bt,   // [E][nbfull][ldb] bf16
    const float* __restrict__ bias,          // [E][nbfull] or null
    unsigned short* __restrict__ Hout,       // [rows][NB_HALF]
    float* __restrict__ out,                 // [N_TOKENS][HIDDEN]
    const int* __restrict__ meta,
    const int* __restrict__ pair_token,
    const float* __restrict__ pair_w,
    int lda, int ldb, int bkoff, int klen, int nbase, int nbfull)
{
  int ntiles = meta[25];

  // T1: bijective XCD-chunked swizzle, rt-major assignment (A/H L2 locality)
  int gx = gridDim.x;
  int nwg = gx * gridDim.y;
  int lid = blockIdx.y * gx + blockIdx.x;
  int q = nwg >> 3, r8 = nwg & 7;
  int xcd = lid & 7, pos = lid >> 3;
  int aid = (xcd < r8 ? xcd * (q + 1) : r8 * (q + 1) + (xcd - r8) * q) + pos;
  int rt = aid / gx;
  int ct = aid % gx;
  if (rt >= ntiles) return;
  int row0 = rt << 8;
  int e = meta[32 + rt];

  __shared__ __align__(16) unsigned short lds[2][4][8192]; // [buf][Alo,Ahi,Blo,Bhi]

  int tid = threadIdx.x;
  int lane = tid & 63, wv = tid >> 6;
  int wm = wv >> 2, wn = wv & 3;
  int quad = lane >> 4, l16 = lane & 15;

  // staging geometry: thread covers global rows {r0c, +64, +128, +192} of A
  // and of B, chunk col (tid&7) linear in global; LDS chunk col swizzled.
  int r0c = tid >> 3;
  int c0c = (tid & 7) ^ (r0c & 7);   // same for all 8 rows handled (row&7 const)
  const unsigned short* Ab = A + (size_t)row0 * lda;
  const unsigned short* Bb = Bt + ((size_t)e * nbfull + nbase + (ct << 8)) * ldb + bkoff;
  const unsigned short* gA0 = Ab + (size_t)r0c * lda + (tid & 7) * 8;   // LINEAR
  const unsigned short* gB0 = Bb + (size_t)r0c * ldb + (tid & 7) * 8;   // LINEAR
  size_t sA = (size_t)64 * lda, sB = (size_t)64 * ldb;

  f32x4 st[8];
  auto LOADS = [&](int k0) {
    st[0] = *(const f32x4*)(gA0 + k0);
    st[1] = *(const f32x4*)(gA0 + sA + k0);
    st[2] = *(const f32x4*)(gA0 + 2 * sA + k0);
    st[3] = *(const f32x4*)(gA0 + 3 * sA + k0);
    st[4] = *(const f32x4*)(gB0 + k0);
    st[5] = *(const f32x4*)(gB0 + sB + k0);
    st[6] = *(const f32x4*)(gB0 + 2 * sB + k0);
    st[7] = *(const f32x4*)(gB0 + 3 * sB + k0);
  };
  auto WRITES = [&](int nb) {
    unsigned short* p = &lds[nb][0][0] + ((size_t)r0c * 8 + c0c) * 8;
    *(f32x4*)(p)         = st[0];   // A slot0 local row r0c
    *(f32x4*)(p + 4096)  = st[1];   // A slot0 local row r0c+64
    *(f32x4*)(p + 8192)  = st[2];   // A slot1 local row r0c
    *(f32x4*)(p + 12288) = st[3];
    *(f32x4*)(p + 16384) = st[4];   // B slot2
    *(f32x4*)(p + 20480) = st[5];
    *(f32x4*)(p + 24576) = st[6];   // B slot3
    *(f32x4*)(p + 28672) = st[7];
  };

  // ds_read per-lane swizzled offsets (shorts); row within slot = mf*32+wm*16+l16
  int swz0 = (quad ^ (l16 & 7)) << 3;
  int swz1 = ((quad ^ 4) ^ (l16 & 7)) << 3;
  int aoff0 = wm * 1024 + l16 * 64 + swz0;
  int aoff1 = wm * 1024 + l16 * 64 + swz1;
  int boff0 = wn * 1024 + l16 * 64 + swz0;
  int boff1 = wn * 1024 + l16 * 64 + swz1;

  f32x4 acc[8][4];
  f32x4 zero = {0.f, 0.f, 0.f, 0.f};
#pragma unroll
  for (int i = 0; i < 8; i++)
#pragma unroll
    for (int j = 0; j < 4; j++) acc[i][j] = zero;

  auto LDA = [&](int bi, int half, short8 (&d)[4][2]) {
    const unsigned short* base = &lds[bi][half][0];
#pragma unroll
    for (int mf = 0; mf < 4; mf++) {
      d[mf][0] = *(const short8*)(base + aoff0 + mf * 2048);
      d[mf][1] = *(const short8*)(base + aoff1 + mf * 2048);
    }
  };
  auto LDB = [&](int bi, int half, short8 (&d)[2][2]) {
    const unsigned short* base = &lds[bi][2 + half][0];
#pragma unroll
    for (int nf = 0; nf < 2; nf++) {
      d[nf][0] = *(const short8*)(base + boff0 + nf * 4096);
      d[nf][1] = *(const short8*)(base + boff1 + nf * 4096);
    }
  };
  auto MM = [&](short8 (&a)[4][2], short8 (&b)[2][2], int mh, int nh) {
#pragma unroll
    for (int mf = 0; mf < 4; mf++)
#pragma unroll
      for (int nf = 0; nf < 2; nf++) {
        f32x4& c = acc[mh * 4 + mf][nh * 2 + nf];
        c = __builtin_amdgcn_mfma_f32_16x16x32_bf16(a[mf][0], b[nf][0], c, 0, 0, 0);
        c = __builtin_amdgcn_mfma_f32_16x16x32_bf16(a[mf][1], b[nf][1], c, 0, 0, 0);
      }
  };

  int NT = klen >> 6;   // 16 (GEMM1) or 32 (GEMM2)

  // prologue: stage tile 0 into buf0 (full-latency stall, once per block)
  LOADS(0);
  WRITES(0);
  LGKM0();
  BAR();

  for (int t = 0; t < NT; t++) {
    int bi = t & 1, nb = bi ^ 1;
    bool pf = (t + 1 < NT);          // block-uniform
    if (pf) LOADS((t + 1) << 6);     // issue prefetch FIRST
    SCHED0();
    short8 aL[4][2], aH[4][2], bL[2][2], bH[2][2];
    LDA(bi, 0, aL); LDB(bi, 0, bL);
    PRIO1; MM(aL, bL, 0, 0); PRIO0;
    LDB(bi, 1, bH);
    PRIO1; MM(aL, bH, 0, 1); PRIO0;
    LDA(bi, 1, aH);
    PRIO1; MM(aH, bL, 1, 0); MM(aH, bH, 1, 1); PRIO0;
    SCHED0();
    if (pf) WRITES(nb);              // compiler-counted vmcnt before writes
    LGKM0();                         // own ds_writes complete
    BAR();                           // one barrier per K-tile
  }

  // epilogue. C/D: col=lane&15, row=quad*4+j. Global row = row0+(mi*2+wm)*16+quad*4+j,
  // global col = ct*256+(ni*4+wn)*16+l16.
  if (EPI == 0) {
#pragma unroll
    for (int mi = 0; mi < 8; mi++) {
      size_t hr = (size_t)row0 + (mi * 2 + wm) * 16 + quad * 4;
#pragma unroll
      for (int ni = 0; ni < 4; ni++) {
        int hcol = (ct << 8) + (ni * 4 + wn) * 16 + l16;
        float bb = bias[(size_t)e * nbfull + nbase + hcol];
#pragma unroll
        for (int j = 0; j < 4; j++) {
          float v = fmaxf(acc[mi][ni][j] + bb, 0.f);
          Hout[(hr + j) * (size_t)NB_HALF + hcol] = f2bf(v);
        }
      }
    }
  } else {
#pragma unroll
    for (int mi = 0; mi < 8; mi++) {
      int rbase = row0 + (mi * 2 + wm) * 16 + quad * 4;
      int tok[4]; float wgt[4];
#pragma unroll
      for (int j = 0; j < 4; j++) {
        tok[j] = pair_token[rbase + j];
        wgt[j] = pair_w[rbase + j];
      }
#pragma unroll
      for (int ni = 0; ni < 4; ni++) {
        int gcol = (ct << 8) + (ni * 4 + wn) * 16 + l16;
        float bb = bias ? bias[(size_t)e * nbfull + gcol] : 0.f;
#pragma unroll
        for (int j = 0; j < 4; j++) {
          if (tok[j] >= 0)
            atomicAdd(out + (size_t)tok[j] * HIDDEN + gcol,
                      wgt[j] * (acc[mi][ni][j] + bb));
        }
      }
    }
  }
}

extern "C" void kernel_launch(void* const* d_in, const int* in_sizes, int n_in,
                              void* d_out, int out_size, void* d_ws, size_t ws_size,
                              hipStream_t stream)
{
  const float* x  = (const float*)d_in[0];
  const float* Wg = (const float*)d_in[1];
  const float* bg = (const float*)d_in[2];
  const float* W1 = (const float*)d_in[3];
  const float* b1 = (const float*)d_in[4];
  const float* W2 = (const float*)d_in[5];
  const float* b2 = (const float*)d_in[6];
  float* out = (float*)d_out;

  // workspace carve-out (~343 MB), 256B aligned chunks
  char* ws = (char*)d_ws;
  size_t off = 0;
  auto alloc = [&](size_t bytes) {
    char* p = ws + off;
    off += (bytes + 255) & ~(size_t)255;
    return p;
  };
  int* gate_idx          = (int*)alloc((size_t)N_TOKENS * 2 * sizeof(int));
  float* gate_w          = (float*)alloc((size_t)N_TOKENS * 2 * sizeof(float));
  int* meta              = (int*)alloc(2048);
  int* blockCounts       = (int*)alloc((size_t)NBLK * N_EXPERTS * sizeof(int));
  int* blockBase         = (int*)alloc((size_t)NBLK * N_EXPERTS * sizeof(int));
  int* pair_token        = (int*)alloc((size_t)MAX_ROWS * sizeof(int));
  float* pair_w          = (float*)alloc((size_t)MAX_ROWS * sizeof(float));
  unsigned short* Xg     = (unsigned short*)alloc((size_t)MAX_ROWS * HIDDEN * 2);
  unsigned short* W1T    = (unsigned short*)alloc((size_t)N_EXPERTS * FFN * HIDDEN * 2);
  unsigned short* W2T    = (unsigned short*)alloc((size_t)N_EXPERTS * HIDDEN * FFN * 2);
  unsigned short* H      = (unsigned short*)alloc((size_t)MAX_ROWS * NB_HALF * 2);

  hipMemsetAsync(pair_token, 0xFF, (size_t)MAX_ROWS * sizeof(int), stream);  // -1
  hipMemsetAsync(out, 0, (size_t)N_TOKENS * HIDDEN * sizeof(float), stream);

  gate_kernel<<<N_TOKENS / 4, 256, 0, stream>>>(x, Wg, bg, gate_idx, gate_w);
  count_kernel<<<NBLK, 256, 0, stream>>>(gate_idx, blockCounts);
  scan_kernel<<<1, 64, 0, stream>>>(blockCounts, blockBase, meta);
  place_kernel<<<NBLK, 256, 0, stream>>>(gate_idx, gate_w, blockBase,
                                         pair_token, pair_w);
  gather_kernel<<<MAX_ROWS, 256, 0, stream>>>(x, pair_token, Xg);
  transpose_bf16_kernel<<<dim3(FFN / 64, HIDDEN / 64, N_EXPERTS), 256, 0, stream>>>(
      W1, W1T, HIDDEN, FFN);
  transpose_bf16_kernel<<<dim3(HIDDEN / 64, FFN / 64, N_EXPERTS), 256, 0, stream>>>(
      W2, W2T, FFN, HIDDEN);

  // FFN-split: for each 2048-wide half of FFN:
  //   G1: H[rows][0:2048] = relu(Xg @ W1T[:, nb:nb+2048] + b1)    (all row tiles)
  //   G2: out += pair_w * (H @ W2T[:, k=nb:nb+2048] + b2?)        (K-partial, atomic)
  for (int fh = 0; fh < 2; fh++) {
    int nb = fh * NB_HALF;
    moe_gemm_kernel<0><<<dim3(NB_HALF / 256, MAX_T), 512, 0, stream>>>(
        Xg, W1T, b1, H, nullptr, meta, nullptr, nullptr,
        HIDDEN, HIDDEN, 0, HIDDEN, nb, FFN);
    moe_gemm_kernel<1><<<dim3(HIDDEN / 256, MAX_T), 512, 0, stream>>>(
        H, W2T, fh == 0 ? b2 : nullptr, nullptr, out, meta, pair_token, pair_w,
        NB_HALF, FFN, nb, NB_HALF, 0, HIDDEN);
  }
}

// Round 5
// 1238.532 us; speedup vs baseline: 1.1937x; 1.1937x over previous
//
#include <hip/hip_runtime.h>
#include <stdint.h>

#define N_TOKENS 16384
#define HIDDEN   1024
#define FFN      4096
#define N_EXPERTS 8
#define NBLK     (N_TOKENS / 256)    // 64 routing blocks
#define MAX_TILES 264                // worst-case 128-row tiles (sum ceil(e/128) <= 264)
#define MAX_ROWS (MAX_TILES * 128)   // 33792
#define NB_HALF  2048                // FFN split width (H is [rows][2048])

typedef __attribute__((ext_vector_type(8))) short short8;
typedef __attribute__((ext_vector_type(4))) float f32x4;

__device__ inline unsigned short f2bf(float f) {
  union { float f; unsigned u; } c; c.f = f;
  unsigned u = c.u;
  unsigned r = (u + 0x7fffu + ((u >> 16) & 1u)) >> 16;  // RNE
  return (unsigned short)r;
}

__device__ inline void gld_lds16(const unsigned short* g, unsigned short* l) {
  __builtin_amdgcn_global_load_lds(
      (const __attribute__((address_space(1))) void*)g,
      (__attribute__((address_space(3))) void*)l, 16, 0, 0);
}

// R0-R4 evidence: five distinct schedules (2-barrier gld_lds, 8-phase
// vmcnt(4), m201 vmcnt(6) ledger, no-clobber ledger, reg-staged 1-barrier)
// all land at 342-375us, MfmaUtil 15-16%. Schedule/ILP falsified. R5 varies
// the one untested axis: OCCUPANCY. 128x128 tile, 32KB single-buffer LDS,
// 256 threads, launch_bounds(256,4) -> 4 blocks/CU (16 waves/CU, 2x prior).
// Cross-block TLP (m114) hides the per-tile latency chain no intra-block
// schedule could.

// ---------------- gate: scores, top-2, softmax ----------------
__global__ __launch_bounds__(256) void gate_kernel(
    const float* __restrict__ x, const float* __restrict__ Wg,
    const float* __restrict__ bg, int* __restrict__ gate_idx,
    float* __restrict__ gate_w)
{
  int lane = threadIdx.x & 63;
  int wv = threadIdx.x >> 6;
  int t = blockIdx.x * 4 + wv;
  const float* xr = x + (size_t)t * HIDDEN;
  float acc[N_EXPERTS];
#pragma unroll
  for (int e = 0; e < N_EXPERTS; e++) acc[e] = 0.f;
#pragma unroll
  for (int i = 0; i < HIDDEN / 64; i++) {
    int h = i * 64 + lane;
    float xv = xr[h];
    const float4* wv4 = (const float4*)(Wg + (size_t)h * N_EXPERTS);
    float4 w01 = wv4[0], w23 = wv4[1];
    acc[0] = fmaf(xv, w01.x, acc[0]); acc[1] = fmaf(xv, w01.y, acc[1]);
    acc[2] = fmaf(xv, w01.z, acc[2]); acc[3] = fmaf(xv, w01.w, acc[3]);
    acc[4] = fmaf(xv, w23.x, acc[4]); acc[5] = fmaf(xv, w23.y, acc[5]);
    acc[6] = fmaf(xv, w23.z, acc[6]); acc[7] = fmaf(xv, w23.w, acc[7]);
  }
#pragma unroll
  for (int off = 32; off > 0; off >>= 1)
#pragma unroll
    for (int e = 0; e < N_EXPERTS; e++)
      acc[e] += __shfl_down(acc[e], off, 64);
  if (lane == 0) {
    float s[N_EXPERTS];
#pragma unroll
    for (int e = 0; e < N_EXPERTS; e++) s[e] = acc[e] + bg[e];
    int e0 = 0;
#pragma unroll
    for (int e = 1; e < N_EXPERTS; e++) if (s[e] > s[e0]) e0 = e;
    int e1 = (e0 == 0) ? 1 : 0;
#pragma unroll
    for (int e = 0; e < N_EXPERTS; e++) if (e != e0 && s[e] > s[e1]) e1 = e;
    float d = s[e1] - s[e0];
    float ex = __expf(d);
    float w0 = 1.f / (1.f + ex);
    float w1 = ex / (1.f + ex);
    gate_idx[2 * t] = e0; gate_idx[2 * t + 1] = e1;
    gate_w[2 * t] = w0;  gate_w[2 * t + 1] = w1;
  }
}

// ---------------- per-block expert histogram ----------------
__global__ __launch_bounds__(256) void count_kernel(
    const int* __restrict__ gate_idx, int* __restrict__ blockCounts)
{
  __shared__ int h[N_EXPERTS];
  if (threadIdx.x < N_EXPERTS) h[threadIdx.x] = 0;
  __syncthreads();
  int t = blockIdx.x * 256 + threadIdx.x;
  atomicAdd(&h[gate_idx[2 * t]], 1);
  atomicAdd(&h[gate_idx[2 * t + 1]], 1);
  __syncthreads();
  if (threadIdx.x < N_EXPERTS)
    blockCounts[blockIdx.x * N_EXPERTS + threadIdx.x] = h[threadIdx.x];
}

// ---------------- scan: 128-aligned expert offsets, tile->expert ----------------
__global__ void scan_kernel(const int* __restrict__ blockCounts,
                            int* __restrict__ blockBase, int* __restrict__ meta)
{
  __shared__ int totals[N_EXPERTS];
  __shared__ int offs[N_EXPERTS + 1];
  int e = threadIdx.x;
  if (e < N_EXPERTS) {
    int run = 0;
    for (int b = 0; b < NBLK; b++) {
      blockBase[b * N_EXPERTS + e] = run;
      run += blockCounts[b * N_EXPERTS + e];
    }
    totals[e] = run;
  }
  __syncthreads();
  if (threadIdx.x == 0) {
    int off = 0;
    for (int ee = 0; ee < N_EXPERTS; ee++) {
      offs[ee] = off;
      meta[16 + ee] = off;
      off += ((totals[ee] + 127) >> 7) << 7;   // 128-aligned (BM=128)
    }
    offs[N_EXPERTS] = off;
    meta[16 + N_EXPERTS] = off;
    int ntiles = off >> 7;
    meta[25] = ntiles;
    int ee = 0;
    for (int t = 0; t < ntiles; t++) {
      while (offs[ee + 1] <= (t << 7)) ee++;
      meta[32 + t] = ee;
    }
  }
  __syncthreads();
  if (e < N_EXPERTS) {
    int o = offs[e];
    for (int b = 0; b < NBLK; b++)
      blockBase[b * N_EXPERTS + e] += o;
  }
}

// ---------------- place: slot assignment via LDS cursors ----------------
__global__ __launch_bounds__(256) void place_kernel(
    const int* __restrict__ gate_idx, const float* __restrict__ gate_w,
    const int* __restrict__ blockBase, int* __restrict__ pair_token,
    float* __restrict__ pair_w)
{
  __shared__ int cur[N_EXPERTS];
  if (threadIdx.x < N_EXPERTS)
    cur[threadIdx.x] = blockBase[blockIdx.x * N_EXPERTS + threadIdx.x];
  __syncthreads();
  int t = blockIdx.x * 256 + threadIdx.x;
#pragma unroll
  for (int k = 0; k < 2; k++) {
    int e = gate_idx[2 * t + k];
    int pos = atomicAdd(&cur[e], 1);
    pair_token[pos] = t;
    pair_w[pos] = gate_w[2 * t + k];
  }
}

// ---------------- gather x rows -> bf16 Xg ----------------
__global__ __launch_bounds__(256) void gather_kernel(
    const float* __restrict__ x, const int* __restrict__ pair_token,
    unsigned short* __restrict__ Xg)
{
  int r = blockIdx.x;
  int t = pair_token[r];
  if (t < 0) return;  // pad row: poison; dropped at GEMM2 epilogue
  const float4* src = (const float4*)(x + (size_t)t * HIDDEN);
  float4 v = src[threadIdx.x];
  ushort4 o;
  o.x = f2bf(v.x); o.y = f2bf(v.y); o.z = f2bf(v.z); o.w = f2bf(v.w);
  ((ushort4*)(Xg + (size_t)r * HIDDEN))[threadIdx.x] = o;
}

// ---------------- transpose + fp32->bf16: in[E][R][C] -> out[E][C][R] ----------------
__global__ __launch_bounds__(256) void transpose_bf16_kernel(
    const float* __restrict__ in, unsigned short* __restrict__ out, int R, int C)
{
  __shared__ float tile[64][65];
  int e = blockIdx.z;
  int r0 = blockIdx.y * 64, c0 = blockIdx.x * 64;
  int tr = threadIdx.x >> 4, tc = threadIdx.x & 15;
  const float* src = in + ((size_t)e * R + r0) * C + c0;
#pragma unroll
  for (int rr = 0; rr < 4; rr++) {
    int row = rr * 16 + tr;
    float4 v = *(const float4*)(src + (size_t)row * C + tc * 4);
    tile[row][tc * 4 + 0] = v.x; tile[row][tc * 4 + 1] = v.y;
    tile[row][tc * 4 + 2] = v.z; tile[row][tc * 4 + 3] = v.w;
  }
  __syncthreads();
  unsigned short* dst = out + ((size_t)e * C + c0) * R + r0;
#pragma unroll
  for (int rr = 0; rr < 4; rr++) {
    int crow = rr * 16 + tr;
    ushort4 o;
    o.x = f2bf(tile[tc * 4 + 0][crow]);
    o.y = f2bf(tile[tc * 4 + 1][crow]);
    o.z = f2bf(tile[tc * 4 + 2][crow]);
    o.w = f2bf(tile[tc * 4 + 3][crow]);
    *(ushort4*)(dst + (size_t)crow * R + tc * 4) = o;
  }
}

// ---------------- 128x128 bf16 GEMM, BK=64, 4 blocks/CU ----------------
// 256 threads = 4 waves (2M x 2N), per-wave 64x64 output, acc[4][4] f32x4.
// LDS: As[128*64] + Bs[128*64] bf16 = 32 KiB single-buffered -> with
// launch_bounds(256,4) (VGPR cap 128) -> 4 blocks/CU, 16 waves/CU.
// Swizzle: 16B-chunk col c ^= (row&7), applied on global SOURCE addresses
// (gld_lds dest linear, rule 21) + identical XOR on ds_read addrs (conflicts=0
// verified R1-R4). Staging: 8 gld_lds16/thread (4 A rows + 4 B rows, +32
// apart; row&7 invariant so source col const). Loop = m97 2-barrier:
//   [bar (drains vm) | ds_read h0 + 16 MFMA | ds_read h1 + 16 MFMA | bar |
//    stage t+1]   -- cross-BLOCK TLP hides the drains.
// EPI=0: H[row][hcol] = bf16(relu(acc+b1))   (A=Xg, N-window of FFN)
// EPI=1: atomicAdd(out[token][col], w*(acc+b2?))  (A=H, K-partial; bias once)
template<int EPI>
__global__ __launch_bounds__(256, 4) void moe_gemm_kernel(
    const unsigned short* __restrict__ A,    // [rows][lda] bf16
    const unsigned short* __restrict__ Bt,   // [E][nbfull][ldb] bf16
    const float* __restrict__ bias,          // [E][nbfull] or null
    unsigned short* __restrict__ Hout,       // [rows][NB_HALF]
    float* __restrict__ out,                 // [N_TOKENS][HIDDEN]
    const int* __restrict__ meta,
    const int* __restrict__ pair_token,
    const float* __restrict__ pair_w,
    int lda, int ldb, int bkoff, int klen, int nbase, int nbfull)
{
  int ntiles = meta[25];

  // T1: bijective XCD-chunked swizzle, rt-major (neighbor blocks share A-tile)
  int gx = gridDim.x;
  int nwg = gx * gridDim.y;
  int lid = blockIdx.y * gx + blockIdx.x;
  int q = nwg >> 3, r8 = nwg & 7;
  int xcd = lid & 7, pos = lid >> 3;
  int aid = (xcd < r8 ? xcd * (q + 1) : r8 * (q + 1) + (xcd - r8) * q) + pos;
  int rt = aid / gx;
  int ct = aid % gx;
  if (rt >= ntiles) return;
  int row0 = rt << 7;
  int e = meta[32 + rt];

  __shared__ __align__(16) unsigned short As[128 * 64];  // 16 KiB
  __shared__ __align__(16) unsigned short Bs[128 * 64];  // 16 KiB

  int tid = threadIdx.x;
  int lane = tid & 63, wv = tid >> 6;
  int wm = wv >> 1, wn = wv & 1;
  int quad = lane >> 4, l16 = lane & 15, l7 = l16 & 7;

  // staging: thread covers rows {r0c, +32, +64, +96} of A and of B,
  // chunk col (tid&7); source col pre-swizzled (row&7 == r0c&7 for all 4).
  int r0c = tid >> 3;
  int csw = ((tid & 7) ^ (r0c & 7)) << 3;   // element offset of swizzled chunk
  const unsigned short* gA = A + (size_t)(row0 + r0c) * lda + csw;
  const unsigned short* gB = Bt + ((size_t)e * nbfull + nbase + (ct << 7) + r0c) * ldb
                             + bkoff + csw;
  unsigned short* lA = As + tid * 8;   // linear dest: chunk idx r0c*8+(tid&7)=tid
  unsigned short* lB = Bs + tid * 8;

  auto STAGE = [&](int k0) {
#pragma unroll
    for (int k = 0; k < 4; k++) {
      gld_lds16(gA + (size_t)(32 * k) * lda + k0, lA + k * 2048);
      gld_lds16(gB + (size_t)(32 * k) * ldb + k0, lB + k * 2048);
    }
  };

  // ds_read offsets: row = w?*64 + frag*16 + l16; chunk = (h*4+quad) ^ l7
  int ca0 = (quad ^ l7) << 3;          // h=0
  int ca1 = ((4 + quad) ^ l7) << 3;    // h=1
  int abase = (wm * 64 + l16) * 64;
  int bbase = (wn * 64 + l16) * 64;

  f32x4 acc[4][4];
  f32x4 zero = {0.f, 0.f, 0.f, 0.f};
#pragma unroll
  for (int i = 0; i < 4; i++)
#pragma unroll
    for (int j = 0; j < 4; j++) acc[i][j] = zero;

  int NT = klen >> 6;

  STAGE(0);
  for (int t = 0; t < NT; t++) {
    __syncthreads();                    // staged data visible (drains vm)
    {
      short8 a[4], b[4];
#pragma unroll
      for (int mf = 0; mf < 4; mf++)
        a[mf] = *(const short8*)(As + abase + mf * 1024 + ca0);
#pragma unroll
      for (int nf = 0; nf < 4; nf++)
        b[nf] = *(const short8*)(Bs + bbase + nf * 1024 + ca0);
#pragma unroll
      for (int mf = 0; mf < 4; mf++)
#pragma unroll
        for (int nf = 0; nf < 4; nf++)
          acc[mf][nf] = __builtin_amdgcn_mfma_f32_16x16x32_bf16(
              a[mf], b[nf], acc[mf][nf], 0, 0, 0);
    }
    {
      short8 a[4], b[4];
#pragma unroll
      for (int mf = 0; mf < 4; mf++)
        a[mf] = *(const short8*)(As + abase + mf * 1024 + ca1);
#pragma unroll
      for (int nf = 0; nf < 4; nf++)
        b[nf] = *(const short8*)(Bs + bbase + nf * 1024 + ca1);
#pragma unroll
      for (int mf = 0; mf < 4; mf++)
#pragma unroll
        for (int nf = 0; nf < 4; nf++)
          acc[mf][nf] = __builtin_amdgcn_mfma_f32_16x16x32_bf16(
              a[mf], b[nf], acc[mf][nf], 0, 0, 0);
    }
    __syncthreads();                    // reads done before restage
    if (t + 1 < NT) STAGE((t + 1) << 6);
  }

  // epilogue. C/D: col=lane&15, row=quad*4+j.
  // global row = row0 + wm*64 + mf*16 + quad*4 + j
  // global col = ct*128 + wn*64 + nf*16 + l16
  if (EPI == 0) {
#pragma unroll
    for (int mf = 0; mf < 4; mf++) {
      size_t hr = (size_t)row0 + wm * 64 + mf * 16 + quad * 4;
#pragma unroll
      for (int nf = 0; nf < 4; nf++) {
        int hcol = (ct << 7) + wn * 64 + nf * 16 + l16;
        float bb = bias[(size_t)e * nbfull + nbase + hcol];
#pragma unroll
        for (int j = 0; j < 4; j++) {
          float v = fmaxf(acc[mf][nf][j] + bb, 0.f);
          Hout[(hr + j) * (size_t)NB_HALF + hcol] = f2bf(v);
        }
      }
    }
  } else {
#pragma unroll
    for (int mf = 0; mf < 4; mf++) {
      int rbase = row0 + wm * 64 + mf * 16 + quad * 4;
      int tok[4]; float wgt[4];
#pragma unroll
      for (int j = 0; j < 4; j++) {
        tok[j] = pair_token[rbase + j];
        wgt[j] = pair_w[rbase + j];
      }
#pragma unroll
      for (int nf = 0; nf < 4; nf++) {
        int gcol = (ct << 7) + wn * 64 + nf * 16 + l16;
        float bb = bias ? bias[(size_t)e * nbfull + gcol] : 0.f;
#pragma unroll
        for (int j = 0; j < 4; j++) {
          if (tok[j] >= 0)
            atomicAdd(out + (size_t)tok[j] * HIDDEN + gcol,
                      wgt[j] * (acc[mf][nf][j] + bb));
        }
      }
    }
  }
}

extern "C" void kernel_launch(void* const* d_in, const int* in_sizes, int n_in,
                              void* d_out, int out_size, void* d_ws, size_t ws_size,
                              hipStream_t stream)
{
  const float* x  = (const float*)d_in[0];
  const float* Wg = (const float*)d_in[1];
  const float* bg = (const float*)d_in[2];
  const float* W1 = (const float*)d_in[3];
  const float* b1 = (const float*)d_in[4];
  const float* W2 = (const float*)d_in[5];
  const float* b2 = (const float*)d_in[6];
  float* out = (float*)d_out;

  // workspace carve-out (~343 MB), 256B aligned chunks
  char* ws = (char*)d_ws;
  size_t off = 0;
  auto alloc = [&](size_t bytes) {
    char* p = ws + off;
    off += (bytes + 255) & ~(size_t)255;
    return p;
  };
  int* gate_idx          = (int*)alloc((size_t)N_TOKENS * 2 * sizeof(int));
  float* gate_w          = (float*)alloc((size_t)N_TOKENS * 2 * sizeof(float));
  int* meta              = (int*)alloc(2048);
  int* blockCounts       = (int*)alloc((size_t)NBLK * N_EXPERTS * sizeof(int));
  int* blockBase         = (int*)alloc((size_t)NBLK * N_EXPERTS * sizeof(int));
  int* pair_token        = (int*)alloc((size_t)MAX_ROWS * sizeof(int));
  float* pair_w          = (float*)alloc((size_t)MAX_ROWS * sizeof(float));
  unsigned short* Xg     = (unsigned short*)alloc((size_t)MAX_ROWS * HIDDEN * 2);
  unsigned short* W1T    = (unsigned short*)alloc((size_t)N_EXPERTS * FFN * HIDDEN * 2);
  unsigned short* W2T    = (unsigned short*)alloc((size_t)N_EXPERTS * HIDDEN * FFN * 2);
  unsigned short* H      = (unsigned short*)alloc((size_t)MAX_ROWS * NB_HALF * 2);

  hipMemsetAsync(pair_token, 0xFF, (size_t)MAX_ROWS * sizeof(int), stream);  // -1
  hipMemsetAsync(out, 0, (size_t)N_TOKENS * HIDDEN * sizeof(float), stream);

  gate_kernel<<<N_TOKENS / 4, 256, 0, stream>>>(x, Wg, bg, gate_idx, gate_w);
  count_kernel<<<NBLK, 256, 0, stream>>>(gate_idx, blockCounts);
  scan_kernel<<<1, 64, 0, stream>>>(blockCounts, blockBase, meta);
  place_kernel<<<NBLK, 256, 0, stream>>>(gate_idx, gate_w, blockBase,
                                         pair_token, pair_w);
  gather_kernel<<<MAX_ROWS, 256, 0, stream>>>(x, pair_token, Xg);
  transpose_bf16_kernel<<<dim3(FFN / 64, HIDDEN / 64, N_EXPERTS), 256, 0, stream>>>(
      W1, W1T, HIDDEN, FFN);
  transpose_bf16_kernel<<<dim3(HIDDEN / 64, FFN / 64, N_EXPERTS), 256, 0, stream>>>(
      W2, W2T, FFN, HIDDEN);

  // FFN-split: for each 2048-wide half of FFN:
  //   G1: H[rows][0:2048] = relu(Xg @ W1T[:, nb:nb+2048] + b1)    (all row tiles)
  //   G2: out += pair_w * (H @ W2T[:, k=nb:nb+2048] + b2?)        (K-partial, atomic)
  for (int fh = 0; fh < 2; fh++) {
    int nb = fh * NB_HALF;
    moe_gemm_kernel<0><<<dim3(NB_HALF / 128, MAX_TILES), 256, 0, stream>>>(
        Xg, W1T, b1, H, nullptr, meta, nullptr, nullptr,
        HIDDEN, HIDDEN, 0, HIDDEN, nb, FFN);
    moe_gemm_kernel<1><<<dim3(HIDDEN / 128, MAX_TILES), 256, 0, stream>>>(
        H, W2T, fh == 0 ? b2 : nullptr, nullptr, out, meta, pair_token, pair_w,
        NB_HALF, FFN, nb, NB_HALF, 0, HIDDEN);
  }
}

// Round 6
// 1189.843 us; speedup vs baseline: 1.2425x; 1.0409x over previous
//
#include <hip/hip_runtime.h>
#include <stdint.h>

#define N_TOKENS 16384
#define HIDDEN   1024
#define FFN      4096
#define N_EXPERTS 8
#define NBLK     (N_TOKENS / 256)    // 64 routing blocks
#define MAX_TILES 264                // worst-case 128-row tiles (sum ceil(e/128) <= 264)
#define MAX_ROWS (MAX_TILES * 128)   // 33792
#define NB_HALF  2048                // FFN split width (H is [rows][2048])

typedef __attribute__((ext_vector_type(8))) short short8;
typedef __attribute__((ext_vector_type(4))) float f32x4;

__device__ inline unsigned short f2bf(float f) {
  union { float f; unsigned u; } c; c.f = f;
  unsigned u = c.u;
  unsigned r = (u + 0x7fffu + ((u >> 16) & 1u)) >> 16;  // RNE
  return (unsigned short)r;
}

__device__ inline void gld_lds16(const unsigned short* g, unsigned short* l) {
  __builtin_amdgcn_global_load_lds(
      (const __attribute__((address_space(1))) void*)g,
      (__attribute__((address_space(3))) void*)l, 16, 0, 0);
}

// R0-R4: five schedules, identical perf -> per-tile latency L (~14k cy) is
// schedule-invariant. R5: occupancy 17->36% cut time 375->255us (throughput
// = C/L confirmed). Binding constraint now: registers (60 VGPR + 64 acc
// AGPR = 124 -> 4 waves/SIMD cap). R6: same structure, 8-wave blocks with
// 64x32 per-wave tiles -> acc 32 AGPR, working ~40 VGPR, launch_bounds
// (512,6) -> cap 80 regs -> 6 waves/SIMD = 3 blocks/CU = 24 waves (75%).

// ---------------- gate: scores, top-2, softmax ----------------
__global__ __launch_bounds__(256) void gate_kernel(
    const float* __restrict__ x, const float* __restrict__ Wg,
    const float* __restrict__ bg, int* __restrict__ gate_idx,
    float* __restrict__ gate_w)
{
  int lane = threadIdx.x & 63;
  int wv = threadIdx.x >> 6;
  int t = blockIdx.x * 4 + wv;
  const float* xr = x + (size_t)t * HIDDEN;
  float acc[N_EXPERTS];
#pragma unroll
  for (int e = 0; e < N_EXPERTS; e++) acc[e] = 0.f;
#pragma unroll
  for (int i = 0; i < HIDDEN / 64; i++) {
    int h = i * 64 + lane;
    float xv = xr[h];
    const float4* wv4 = (const float4*)(Wg + (size_t)h * N_EXPERTS);
    float4 w01 = wv4[0], w23 = wv4[1];
    acc[0] = fmaf(xv, w01.x, acc[0]); acc[1] = fmaf(xv, w01.y, acc[1]);
    acc[2] = fmaf(xv, w01.z, acc[2]); acc[3] = fmaf(xv, w01.w, acc[3]);
    acc[4] = fmaf(xv, w23.x, acc[4]); acc[5] = fmaf(xv, w23.y, acc[5]);
    acc[6] = fmaf(xv, w23.z, acc[6]); acc[7] = fmaf(xv, w23.w, acc[7]);
  }
#pragma unroll
  for (int off = 32; off > 0; off >>= 1)
#pragma unroll
    for (int e = 0; e < N_EXPERTS; e++)
      acc[e] += __shfl_down(acc[e], off, 64);
  if (lane == 0) {
    float s[N_EXPERTS];
#pragma unroll
    for (int e = 0; e < N_EXPERTS; e++) s[e] = acc[e] + bg[e];
    int e0 = 0;
#pragma unroll
    for (int e = 1; e < N_EXPERTS; e++) if (s[e] > s[e0]) e0 = e;
    int e1 = (e0 == 0) ? 1 : 0;
#pragma unroll
    for (int e = 0; e < N_EXPERTS; e++) if (e != e0 && s[e] > s[e1]) e1 = e;
    float d = s[e1] - s[e0];
    float ex = __expf(d);
    float w0 = 1.f / (1.f + ex);
    float w1 = ex / (1.f + ex);
    gate_idx[2 * t] = e0; gate_idx[2 * t + 1] = e1;
    gate_w[2 * t] = w0;  gate_w[2 * t + 1] = w1;
  }
}

// ---------------- per-block expert histogram ----------------
__global__ __launch_bounds__(256) void count_kernel(
    const int* __restrict__ gate_idx, int* __restrict__ blockCounts)
{
  __shared__ int h[N_EXPERTS];
  if (threadIdx.x < N_EXPERTS) h[threadIdx.x] = 0;
  __syncthreads();
  int t = blockIdx.x * 256 + threadIdx.x;
  atomicAdd(&h[gate_idx[2 * t]], 1);
  atomicAdd(&h[gate_idx[2 * t + 1]], 1);
  __syncthreads();
  if (threadIdx.x < N_EXPERTS)
    blockCounts[blockIdx.x * N_EXPERTS + threadIdx.x] = h[threadIdx.x];
}

// ---------------- scan: 128-aligned expert offsets, tile->expert ----------------
__global__ void scan_kernel(const int* __restrict__ blockCounts,
                            int* __restrict__ blockBase, int* __restrict__ meta)
{
  __shared__ int totals[N_EXPERTS];
  __shared__ int offs[N_EXPERTS + 1];
  int e = threadIdx.x;
  if (e < N_EXPERTS) {
    int run = 0;
    for (int b = 0; b < NBLK; b++) {
      blockBase[b * N_EXPERTS + e] = run;
      run += blockCounts[b * N_EXPERTS + e];
    }
    totals[e] = run;
  }
  __syncthreads();
  if (threadIdx.x == 0) {
    int off = 0;
    for (int ee = 0; ee < N_EXPERTS; ee++) {
      offs[ee] = off;
      meta[16 + ee] = off;
      off += ((totals[ee] + 127) >> 7) << 7;   // 128-aligned (BM=128)
    }
    offs[N_EXPERTS] = off;
    meta[16 + N_EXPERTS] = off;
    int ntiles = off >> 7;
    meta[25] = ntiles;
    int ee = 0;
    for (int t = 0; t < ntiles; t++) {
      while (offs[ee + 1] <= (t << 7)) ee++;
      meta[32 + t] = ee;
    }
  }
  __syncthreads();
  if (e < N_EXPERTS) {
    int o = offs[e];
    for (int b = 0; b < NBLK; b++)
      blockBase[b * N_EXPERTS + e] += o;
  }
}

// ---------------- place: slot assignment via LDS cursors ----------------
__global__ __launch_bounds__(256) void place_kernel(
    const int* __restrict__ gate_idx, const float* __restrict__ gate_w,
    const int* __restrict__ blockBase, int* __restrict__ pair_token,
    float* __restrict__ pair_w)
{
  __shared__ int cur[N_EXPERTS];
  if (threadIdx.x < N_EXPERTS)
    cur[threadIdx.x] = blockBase[blockIdx.x * N_EXPERTS + threadIdx.x];
  __syncthreads();
  int t = blockIdx.x * 256 + threadIdx.x;
#pragma unroll
  for (int k = 0; k < 2; k++) {
    int e = gate_idx[2 * t + k];
    int pos = atomicAdd(&cur[e], 1);
    pair_token[pos] = t;
    pair_w[pos] = gate_w[2 * t + k];
  }
}

// ---------------- gather x rows -> bf16 Xg ----------------
__global__ __launch_bounds__(256) void gather_kernel(
    const float* __restrict__ x, const int* __restrict__ pair_token,
    unsigned short* __restrict__ Xg)
{
  int r = blockIdx.x;
  int t = pair_token[r];
  if (t < 0) return;  // pad row: poison; dropped at GEMM2 epilogue
  const float4* src = (const float4*)(x + (size_t)t * HIDDEN);
  float4 v = src[threadIdx.x];
  ushort4 o;
  o.x = f2bf(v.x); o.y = f2bf(v.y); o.z = f2bf(v.z); o.w = f2bf(v.w);
  ((ushort4*)(Xg + (size_t)r * HIDDEN))[threadIdx.x] = o;
}

// ---------------- transpose + fp32->bf16: in[E][R][C] -> out[E][C][R] ----------------
__global__ __launch_bounds__(256) void transpose_bf16_kernel(
    const float* __restrict__ in, unsigned short* __restrict__ out, int R, int C)
{
  __shared__ float tile[64][65];
  int e = blockIdx.z;
  int r0 = blockIdx.y * 64, c0 = blockIdx.x * 64;
  int tr = threadIdx.x >> 4, tc = threadIdx.x & 15;
  const float* src = in + ((size_t)e * R + r0) * C + c0;
#pragma unroll
  for (int rr = 0; rr < 4; rr++) {
    int row = rr * 16 + tr;
    float4 v = *(const float4*)(src + (size_t)row * C + tc * 4);
    tile[row][tc * 4 + 0] = v.x; tile[row][tc * 4 + 1] = v.y;
    tile[row][tc * 4 + 2] = v.z; tile[row][tc * 4 + 3] = v.w;
  }
  __syncthreads();
  unsigned short* dst = out + ((size_t)e * C + c0) * R + r0;
#pragma unroll
  for (int rr = 0; rr < 4; rr++) {
    int crow = rr * 16 + tr;
    ushort4 o;
    o.x = f2bf(tile[tc * 4 + 0][crow]);
    o.y = f2bf(tile[tc * 4 + 1][crow]);
    o.z = f2bf(tile[tc * 4 + 2][crow]);
    o.w = f2bf(tile[tc * 4 + 3][crow]);
    *(ushort4*)(dst + (size_t)crow * R + tc * 4) = o;
  }
}

// ---------------- 128x128 bf16 GEMM, BK=64, 8 waves, 3 blocks/CU ----------------
// 512 threads = 8 waves (2M x 4N), per-wave 64x32 output, acc[4][2] f32x4
// (32 AGPR). LDS: As[128*64]+Bs[128*64] = 32 KiB single-buffered.
// launch_bounds(512,6): cap 80 regs -> 6 waves/SIMD -> 3 blocks/CU (24
// waves/CU, 75%). Swizzle: 16B-chunk col ^= (row&7) on global SOURCE
// (gld_lds dest linear) + same XOR on ds_read (conflicts=0, R1-R5).
// Staging: 4 gld_lds16/thread (2 A + 2 B rows, +64 apart; row&7 invariant).
// Loop = 2-barrier m97: [bar | ds_read+MFMA h0,h1 | bar | stage t+1].
// EPI=0: H[row][hcol] = bf16(relu(acc+b1))   (A=Xg, N-window of FFN)
// EPI=1: atomicAdd(out[token][col], w*(acc+b2?))  (A=H, K-partial; bias once)
template<int EPI>
__global__ __launch_bounds__(512, 6) void moe_gemm_kernel(
    const unsigned short* __restrict__ A,    // [rows][lda] bf16
    const unsigned short* __restrict__ Bt,   // [E][nbfull][ldb] bf16
    const float* __restrict__ bias,          // [E][nbfull] or null
    unsigned short* __restrict__ Hout,       // [rows][NB_HALF]
    float* __restrict__ out,                 // [N_TOKENS][HIDDEN]
    const int* __restrict__ meta,
    const int* __restrict__ pair_token,
    const float* __restrict__ pair_w,
    int lda, int ldb, int bkoff, int klen, int nbase, int nbfull)
{
  int ntiles = meta[25];

  // T1: bijective XCD-chunked swizzle, rt-major (neighbor blocks share A-tile)
  int gx = gridDim.x;
  int nwg = gx * gridDim.y;
  int lid = blockIdx.y * gx + blockIdx.x;
  int q = nwg >> 3, r8 = nwg & 7;
  int xcd = lid & 7, pos = lid >> 3;
  int aid = (xcd < r8 ? xcd * (q + 1) : r8 * (q + 1) + (xcd - r8) * q) + pos;
  int rt = aid / gx;
  int ct = aid % gx;
  if (rt >= ntiles) return;
  int row0 = rt << 7;
  int e = meta[32 + rt];

  __shared__ __align__(16) unsigned short As[128 * 64];  // 16 KiB
  __shared__ __align__(16) unsigned short Bs[128 * 64];  // 16 KiB

  int tid = threadIdx.x;
  int lane = tid & 63, wv = tid >> 6;
  int wm = wv >> 2, wn = wv & 3;
  int quad = lane >> 4, l16 = lane & 15, l7 = l16 & 7;

  // staging: thread covers rows {r0c, r0c+64} of A and of B, chunk col
  // (tid&7); source col pre-swizzled (row&7 invariant across +64).
  int r0c = tid >> 3;
  int csw = ((tid & 7) ^ (r0c & 7)) << 3;
  const unsigned short* gA = A + (size_t)(row0 + r0c) * lda + csw;
  const unsigned short* gB = Bt + ((size_t)e * nbfull + nbase + (ct << 7) + r0c) * ldb
                             + bkoff + csw;
  unsigned short* lA = As + tid * 8;   // linear dest: chunk idx = tid
  unsigned short* lB = Bs + tid * 8;

  auto STAGE = [&](int k0) {
    gld_lds16(gA + k0, lA);
    gld_lds16(gA + (size_t)64 * lda + k0, lA + 4096);
    gld_lds16(gB + k0, lB);
    gld_lds16(gB + (size_t)64 * ldb + k0, lB + 4096);
  };

  // ds_read offsets: A row = wm*64 + mf*16 + l16; B row = wn*32 + nf*16 + l16
  // chunk = (h*4+quad) ^ l7
  int ca0 = (quad ^ l7) << 3;          // k-half 0
  int ca1 = ((4 + quad) ^ l7) << 3;    // k-half 1
  int abase = (wm * 64 + l16) * 64;
  int bbase = (wn * 32 + l16) * 64;

  f32x4 acc[4][2];
  f32x4 zero = {0.f, 0.f, 0.f, 0.f};
#pragma unroll
  for (int i = 0; i < 4; i++)
#pragma unroll
    for (int j = 0; j < 2; j++) acc[i][j] = zero;

  int NT = klen >> 6;

  STAGE(0);
  for (int t = 0; t < NT; t++) {
    __syncthreads();                    // staged data visible (drains vm)
#pragma unroll
    for (int h = 0; h < 2; h++) {
      int ca = h ? ca1 : ca0;
      short8 a[4], b[2];
#pragma unroll
      for (int nf = 0; nf < 2; nf++)
        b[nf] = *(const short8*)(Bs + bbase + nf * 1024 + ca);
#pragma unroll
      for (int mf = 0; mf < 4; mf++)
        a[mf] = *(const short8*)(As + abase + mf * 1024 + ca);
#pragma unroll
      for (int mf = 0; mf < 4; mf++)
#pragma unroll
        for (int nf = 0; nf < 2; nf++)
          acc[mf][nf] = __builtin_amdgcn_mfma_f32_16x16x32_bf16(
              a[mf], b[nf], acc[mf][nf], 0, 0, 0);
    }
    __syncthreads();                    // reads done before restage
    if (t + 1 < NT) STAGE((t + 1) << 6);
  }

  // epilogue. C/D: col=lane&15, row=quad*4+j.
  // global row = row0 + wm*64 + mf*16 + quad*4 + j
  // global col = ct*128 + wn*32 + nf*16 + l16
  if (EPI == 0) {
#pragma unroll
    for (int mf = 0; mf < 4; mf++) {
      size_t hr = (size_t)row0 + wm * 64 + mf * 16 + quad * 4;
#pragma unroll
      for (int nf = 0; nf < 2; nf++) {
        int hcol = (ct << 7) + wn * 32 + nf * 16 + l16;
        float bb = bias[(size_t)e * nbfull + nbase + hcol];
#pragma unroll
        for (int j = 0; j < 4; j++) {
          float v = fmaxf(acc[mf][nf][j] + bb, 0.f);
          Hout[(hr + j) * (size_t)NB_HALF + hcol] = f2bf(v);
        }
      }
    }
  } else {
#pragma unroll
    for (int mf = 0; mf < 4; mf++) {
      int rbase = row0 + wm * 64 + mf * 16 + quad * 4;
      int tok[4]; float wgt[4];
#pragma unroll
      for (int j = 0; j < 4; j++) {
        tok[j] = pair_token[rbase + j];
        wgt[j] = pair_w[rbase + j];
      }
#pragma unroll
      for (int nf = 0; nf < 2; nf++) {
        int gcol = (ct << 7) + wn * 32 + nf * 16 + l16;
        float bb = bias ? bias[(size_t)e * nbfull + gcol] : 0.f;
#pragma unroll
        for (int j = 0; j < 4; j++) {
          if (tok[j] >= 0)
            atomicAdd(out + (size_t)tok[j] * HIDDEN + gcol,
                      wgt[j] * (acc[mf][nf][j] + bb));
        }
      }
    }
  }
}

extern "C" void kernel_launch(void* const* d_in, const int* in_sizes, int n_in,
                              void* d_out, int out_size, void* d_ws, size_t ws_size,
                              hipStream_t stream)
{
  const float* x  = (const float*)d_in[0];
  const float* Wg = (const float*)d_in[1];
  const float* bg = (const float*)d_in[2];
  const float* W1 = (const float*)d_in[3];
  const float* b1 = (const float*)d_in[4];
  const float* W2 = (const float*)d_in[5];
  const float* b2 = (const float*)d_in[6];
  float* out = (float*)d_out;

  // workspace carve-out (~343 MB), 256B aligned chunks
  char* ws = (char*)d_ws;
  size_t off = 0;
  auto alloc = [&](size_t bytes) {
    char* p = ws + off;
    off += (bytes + 255) & ~(size_t)255;
    return p;
  };
  int* gate_idx          = (int*)alloc((size_t)N_TOKENS * 2 * sizeof(int));
  float* gate_w          = (float*)alloc((size_t)N_TOKENS * 2 * sizeof(float));
  int* meta              = (int*)alloc(2048);
  int* blockCounts       = (int*)alloc((size_t)NBLK * N_EXPERTS * sizeof(int));
  int* blockBase         = (int*)alloc((size_t)NBLK * N_EXPERTS * sizeof(int));
  int* pair_token        = (int*)alloc((size_t)MAX_ROWS * sizeof(int));
  float* pair_w          = (float*)alloc((size_t)MAX_ROWS * sizeof(float));
  unsigned short* Xg     = (unsigned short*)alloc((size_t)MAX_ROWS * HIDDEN * 2);
  unsigned short* W1T    = (unsigned short*)alloc((size_t)N_EXPERTS * FFN * HIDDEN * 2);
  unsigned short* W2T    = (unsigned short*)alloc((size_t)N_EXPERTS * HIDDEN * FFN * 2);
  unsigned short* H      = (unsigned short*)alloc((size_t)MAX_ROWS * NB_HALF * 2);

  hipMemsetAsync(pair_token, 0xFF, (size_t)MAX_ROWS * sizeof(int), stream);  // -1
  hipMemsetAsync(out, 0, (size_t)N_TOKENS * HIDDEN * sizeof(float), stream);

  gate_kernel<<<N_TOKENS / 4, 256, 0, stream>>>(x, Wg, bg, gate_idx, gate_w);
  count_kernel<<<NBLK, 256, 0, stream>>>(gate_idx, blockCounts);
  scan_kernel<<<1, 64, 0, stream>>>(blockCounts, blockBase, meta);
  place_kernel<<<NBLK, 256, 0, stream>>>(gate_idx, gate_w, blockBase,
                                         pair_token, pair_w);
  gather_kernel<<<MAX_ROWS, 256, 0, stream>>>(x, pair_token, Xg);
  transpose_bf16_kernel<<<dim3(FFN / 64, HIDDEN / 64, N_EXPERTS), 256, 0, stream>>>(
      W1, W1T, HIDDEN, FFN);
  transpose_bf16_kernel<<<dim3(HIDDEN / 64, FFN / 64, N_EXPERTS), 256, 0, stream>>>(
      W2, W2T, FFN, HIDDEN);

  // FFN-split: for each 2048-wide half of FFN:
  //   G1: H[rows][0:2048] = relu(Xg @ W1T[:, nb:nb+2048] + b1)    (all row tiles)
  //   G2: out += pair_w * (H @ W2T[:, k=nb:nb+2048] + b2?)        (K-partial, atomic)
  for (int fh = 0; fh < 2; fh++) {
    int nb = fh * NB_HALF;
    moe_gemm_kernel<0><<<dim3(NB_HALF / 128, MAX_TILES), 512, 0, stream>>>(
        Xg, W1T, b1, H, nullptr, meta, nullptr, nullptr,
        HIDDEN, HIDDEN, 0, HIDDEN, nb, FFN);
    moe_gemm_kernel<1><<<dim3(HIDDEN / 128, MAX_TILES), 512, 0, stream>>>(
        H, W2T, fh == 0 ? b2 : nullptr, nullptr, out, meta, pair_token, pair_w,
        NB_HALF, FFN, nb, NB_HALF, 0, HIDDEN);
  }
}